// Round 5
// baseline (160.354 us; speedup 1.0000x reference)
//
#include <hip/hip_runtime.h>
#include <math.h>

// Problem constants (match reference)
#define BATCH 1024
#define NV    64      // N_VARS
#define MC    256     // M_CLAUSES
#define KD    12      // K_DIM
#define PI_F  3.14159265358979323846f

// Compact permuted C layout (floats, per m-split copy):
//   rows: 64 x 64. Row q = Gram row of var v = (q+1)%64+1 (0-based target
//     jv = (q+1)&63), with 0-based cols {jv, jv-1, jv-2} (wrapped) PRE-ZEROED.
//   Within-row position perm(j0) = (j0&15)*4 + (j0>>4) so lane group
//   jg = l&15 reads a CONTIGUOUS 4-float slice (j0 === jg mod 16) = 1 b128.
//   c0N[64]  at C0OFF : c0N[q]   = C[v][0]
//   DgA[64]  at DGAOFF: DgA[v-1] = C[v][prev1(v)]  -> readlane i gives C[i][i-1]
//   DgB[64]  at DGBOFF: DgB[v-1] = C[v][prev2(v)]  -> readlane i gives C[i][i-2]
#define C0OFF  4096
#define DGAOFF 4160
#define DGBOFF 4224
#define CBUF   4288

typedef float f2  __attribute__((ext_vector_type(2)));
typedef float v4f __attribute__((ext_vector_type(4)));
typedef __attribute__((address_space(3))) float lds_f;

// ---- DPP add helpers (bound_ctrl=true, old=0 -> GCNDPPCombine-fusable) ----
// 0xB1 quad xor1, 0x4E quad xor2, 0x124 row_ror:4, 0x128 row_ror:8,
// 0x142 row_bcast15, 0x143 row_bcast31.
template <int CTRL>
__device__ __forceinline__ float dpp_addf(float x) {
  int y = __builtin_amdgcn_update_dpp(0, __float_as_int(x), CTRL, 0xF, 0xF, true);
  return x + __int_as_float(y);
}
__device__ __forceinline__ float readlane63(float x) {
  return __int_as_float(__builtin_amdgcn_readlane(__float_as_int(x), 63));
}
__device__ __forceinline__ float rlane(float x, int i) {
  return __int_as_float(__builtin_amdgcn_readlane(__float_as_int(x), i));
}

// Async LDS read: volatile pins the ISSUE point; counted s_waitcnt carries the
// consume-side ordering through REGISTER deps ("+v" on the slot), no memory
// clobber / sched_barrier -> independent work schedules freely across steps.
template <int IMM>
__device__ __forceinline__ void dsr(v4f& d, unsigned base) {
  asm volatile("ds_read_b128 %0, %1 offset:%2" : "=v"(d) : "v"(base), "i"(IMM));
}

// ---- Kernel 1: Gram rows (permuted, pre-zeroed cols) + c0/dgA/dgB tables ----
__global__ void compute_C_kernel(const float* __restrict__ S,
                                 const float* __restrict__ w,
                                 float* __restrict__ Cg, int nsplit) {
  const int q = blockIdx.x;
  const int mc = blockIdx.y;
  const int j = threadIdx.x;  // column 0..64 (1-based vars; 0 = e0 row)
  if (j > NV) return;
  const int v = (q + 1) % 64 + 1;
  const int mlen = MC / nsplit;
  const int m0 = mc * mlen;
  float a0 = 0.f, a1 = 0.f, a2 = 0.f, a3 = 0.f;
  for (int m = m0; m < m0 + mlen; m += 4) {
    const float w0 = w[m], w1 = w[m + 1], w2 = w[m + 2], w3 = w[m + 3];
    a0 = fmaf(S[(m + 0) * (NV + 1) + v] * w0 * w0, S[(m + 0) * (NV + 1) + j], a0);
    a1 = fmaf(S[(m + 1) * (NV + 1) + v] * w1 * w1, S[(m + 1) * (NV + 1) + j], a1);
    a2 = fmaf(S[(m + 2) * (NV + 1) + v] * w2 * w2, S[(m + 2) * (NV + 1) + j], a2);
    a3 = fmaf(S[(m + 3) * (NV + 1) + v] * w3 * w3, S[(m + 3) * (NV + 1) + j], a3);
  }
  const float acc = (a0 + a1) + (a2 + a3);
  float* buf = Cg + mc * CBUF;
  const int p1 = (v == 1) ? 64 : (v - 1);
  const int p2 = (v == 1) ? 63 : (v == 2) ? 64 : (v - 2);
  if (j == 0) buf[C0OFF + q] = acc;
  if (j == p1) buf[DGAOFF + (v - 1)] = acc;
  if (j == p2) buf[DGBOFF + (v - 1)] = acc;
  if (j > 0) {
    const int j0 = j - 1;  // 0-based var column
    const float st = (j == v || j == p1 || j == p2) ? 0.f : acc;
    buf[q * 64 + (j0 & 15) * 4 + (j0 >> 4)] = st;  // permuted position
  }
}

// ---- Kernel 2: (jg16, k-quad) mixing, 1 ds_read_b128/step ----------------
// Block = 256 thr = 4 waves = 4 batches, shared LDS C.
// Lane l: jg = l&15 owns vars j === jg (mod 16); kq = l>>4 owns k-quad
// {4kq..4kq+3} (kq=3 -> k 12..15 zero-pad, self-consistently 0).
// Per lane: Va[4]/Vb[4] f2: Va[m] = V[jg+16m][{4kq,4kq+1}], Vb = k {+2,+3}.
// Carries Pa/Pb (=Q_i), vp1*/vp2* (u_{i-1},u_{i-2} k-quad slices, row-uniform).
// Per step: g = P + da*vp1 + db*vp2 (4 pk) -> n2 local dot4 (row-uniform!)
// -> 0x142+0x143+readlane63 -> rsq -> vn; Q_{i+1} = 8 pk_fma products +
// 16-lane butterfly (4 hops x 4 subregs) + e0; delayed writeback of u_{i-1}.
__global__ __launch_bounds__(256, 1) void mixing_kernel(
    const float* __restrict__ z, const float* __restrict__ r,
    const float* __restrict__ Cg, const int* __restrict__ max_iter_p,
    float* __restrict__ out, int nsplit) {
  __shared__ __align__(16) float Ls[CBUF];  // 17152 B

  const int t = threadIdx.x;
  const int l = t & 63;
  const int jg = l & 15;
  const int kq = l >> 4;
  const int b = blockIdx.x * 4 + (t >> 6);
  const int max_iter = max_iter_p[0];

  // stage (and m-split-reduce) compact C into LDS
  {
    const float4* src = (const float4*)Cg;
    float4* dst = (float4*)Ls;
    for (int idx = t; idx < CBUF / 4; idx += 256) {
      float4 a = src[idx];
      for (int u = 1; u < nsplit; ++u) {
        const float4 p = src[u * (CBUF / 4) + idx];
        a.x += p.x; a.y += p.y; a.z += p.z; a.w += p.w;
      }
      dst[idx] = a;
    }
  }

  const float my_e0 = (kq == 0) ? 1.f : 0.f;

  // ---- init: V[j][k] = -cos(pi z_j) [k=0] + sin(pi z_j) * rp_hat[k] ----
  f2 Va[4], Vb[4];
  #pragma unroll
  for (int m = 0; m < 4; ++m) {
    const int j0 = jg + 16 * m;
    const float zv = z[b * NV + j0];
    v4f rp4 = {0.f, 0.f, 0.f, 0.f};
    if (kq < 3) rp4 = *(const v4f*)&r[(b * NV + j0) * KD + 4 * kq];
    if (kq == 0) rp4.x = 0.f;  // k=0 excluded from r_perp
    float ssp = rp4.x * rp4.x;
    ssp = fmaf(rp4.y, rp4.y, ssp);
    ssp = fmaf(rp4.z, rp4.z, ssp);
    ssp = fmaf(rp4.w, rp4.w, ssp);
    ssp += __shfl_xor(ssp, 16, 64);
    ssp += __shfl_xor(ssp, 32, 64);
    const float inv = 1.f / fmaxf(sqrtf(ssp), 1e-8f);
    const float sn = __builtin_amdgcn_sinf(0.5f * zv);  // sin(pi*z)
    const float cs = __builtin_amdgcn_cosf(0.5f * zv);  // cos(pi*z)
    const float si = sn * inv;
    Va[m].x = (kq == 0) ? -cs : si * rp4.x;
    Va[m].y = si * rp4.y;
    Vb[m].x = si * rp4.z;
    Vb[m].y = si * rp4.w;
  }

  __syncthreads();

  // lane-distributed tables: lane x holds c0N[x], DgA[x], DgB[x]
  const float t0v = Ls[C0OFF + l];
  const float t1v = Ls[DGAOFF + l];
  const float t2v = Ls[DGBOFF + l];

  f2 Pa, Pb, vp1a, vp1b, vp2a, vp2b;

  // ---- prologue: Q from row 63; vp1/vp2 = V_init[63/62][k-quad] ----
  {
    const v4f ce = *(const v4f*)&Ls[63 * 64 + jg * 4];
    f2 qa = (f2){ce.x, ce.x} * Va[0];
    f2 qb = (f2){ce.x, ce.x} * Vb[0];
    qa = __builtin_elementwise_fma((f2){ce.y, ce.y}, Va[1], qa);
    qb = __builtin_elementwise_fma((f2){ce.y, ce.y}, Vb[1], qb);
    qa = __builtin_elementwise_fma((f2){ce.z, ce.z}, Va[2], qa);
    qb = __builtin_elementwise_fma((f2){ce.z, ce.z}, Vb[2], qb);
    qa = __builtin_elementwise_fma((f2){ce.w, ce.w}, Va[3], qa);
    qb = __builtin_elementwise_fma((f2){ce.w, ce.w}, Vb[3], qb);
    qa.x = dpp_addf<0xB1>(qa.x); qa.y = dpp_addf<0xB1>(qa.y);
    qb.x = dpp_addf<0xB1>(qb.x); qb.y = dpp_addf<0xB1>(qb.y);
    qa.x = dpp_addf<0x4E>(qa.x); qa.y = dpp_addf<0x4E>(qa.y);
    qb.x = dpp_addf<0x4E>(qb.x); qb.y = dpp_addf<0x4E>(qb.y);
    qa.x = dpp_addf<0x124>(qa.x); qa.y = dpp_addf<0x124>(qa.y);
    qb.x = dpp_addf<0x124>(qb.x); qb.y = dpp_addf<0x124>(qb.y);
    qa.x = dpp_addf<0x128>(qa.x); qa.y = dpp_addf<0x128>(qa.y);
    qb.x = dpp_addf<0x128>(qb.x); qb.y = dpp_addf<0x128>(qb.y);
    qa.x = fmaf(my_e0, Ls[C0OFF + 63], qa.x);
    Pa = qa; Pb = qb;
    // j0=63 -> (jg=15, m=3); j0=62 -> (jg=14, m=3); same-kq row lane.
    const int rowb = l & 48;
    vp1a.x = __shfl(Va[3].x, rowb | 15, 64);
    vp1a.y = __shfl(Va[3].y, rowb | 15, 64);
    vp1b.x = __shfl(Vb[3].x, rowb | 15, 64);
    vp1b.y = __shfl(Vb[3].y, rowb | 15, 64);
    vp2a.x = __shfl(Va[3].x, rowb | 14, 64);
    vp2a.y = __shfl(Va[3].y, rowb | 14, 64);
    vp2b.x = __shfl(Vb[3].x, rowb | 14, 64);
    vp2b.y = __shfl(Vb[3].y, rowb | 14, 64);
  }

  // LDS byte base for this lane's 16B row slice
  const unsigned lbase = (unsigned)(unsigned long long)(lds_f*)&Ls[jg * 4];

  v4f Rb[4];  // 4-slot register ring, one b128 per row, compile-time indexed

#define PFROW(R) dsr<(((R) & 63) * 256)>(Rb[(R) & 3], lbase);

// Counted wait expressed through REGISTER deps on the consumed slot.
#define WAITR(SL) asm volatile("s_waitcnt lgkmcnt(2)" : "+v"(Rb[SL]));

#define STEPF(I) { \
  constexpr int i_ = (I); \
  constexpr int j0w_ = (i_ + 63) & 63; \
  constexpr int m_ = j0w_ >> 4; \
  constexpr int jgo_ = j0w_ & 15; \
  constexpr int s_ = i_ & 3; \
  WAITR(s_) \
  PFROW(i_ + 3) \
  const float da_ = rlane(t1v, i_); \
  const float db_ = rlane(t2v, i_); \
  const float c0_ = rlane(t0v, i_); \
  /* chain head: the true recurrence */ \
  f2 ga_ = __builtin_elementwise_fma((f2){db_, db_}, vp2a, Pa); \
  f2 gb_ = __builtin_elementwise_fma((f2){db_, db_}, vp2b, Pb); \
  ga_ = __builtin_elementwise_fma((f2){da_, da_}, vp1a, ga_); \
  gb_ = __builtin_elementwise_fma((f2){da_, da_}, vp1b, gb_); \
  f2 tp_ = ga_ * ga_; \
  tp_ = __builtin_elementwise_fma(gb_, gb_, tp_); \
  float t_ = tp_.x + tp_.y;  /* row-uniform partial over this k-quad */ \
  /* products (independent) interleaved with n2's 2-hop + tail */ \
  const v4f ce_ = Rb[s_]; \
  f2 qa_ = (f2){ce_.x, ce_.x} * Va[0]; \
  f2 qb_ = (f2){ce_.x, ce_.x} * Vb[0]; \
  t_ = dpp_addf<0x142>(t_); \
  qa_ = __builtin_elementwise_fma((f2){ce_.y, ce_.y}, Va[1], qa_); \
  qb_ = __builtin_elementwise_fma((f2){ce_.y, ce_.y}, Vb[1], qb_); \
  t_ = dpp_addf<0x143>(t_); \
  qa_ = __builtin_elementwise_fma((f2){ce_.z, ce_.z}, Va[2], qa_); \
  qb_ = __builtin_elementwise_fma((f2){ce_.z, ce_.z}, Vb[2], qb_); \
  const float n2_ = readlane63(t_); \
  qa_ = __builtin_elementwise_fma((f2){ce_.w, ce_.w}, Va[3], qa_); \
  qb_ = __builtin_elementwise_fma((f2){ce_.w, ce_.w}, Vb[3], qb_); \
  const float inv_ = __builtin_amdgcn_rsqf(fmaxf(n2_, 1e-16f)); \
  const f2 ni_ = {-inv_, -inv_}; \
  const f2 vna_ = ga_ * ni_; \
  const f2 vnb_ = gb_ * ni_; \
  /* q-reduce over 16 jg lanes: 4 hops x 4 subregs (fills rsq shadow) */ \
  qa_.x = dpp_addf<0xB1>(qa_.x); qa_.y = dpp_addf<0xB1>(qa_.y); \
  qb_.x = dpp_addf<0xB1>(qb_.x); qb_.y = dpp_addf<0xB1>(qb_.y); \
  qa_.x = dpp_addf<0x4E>(qa_.x); qa_.y = dpp_addf<0x4E>(qa_.y); \
  qb_.x = dpp_addf<0x4E>(qb_.x); qb_.y = dpp_addf<0x4E>(qb_.y); \
  qa_.x = dpp_addf<0x124>(qa_.x); qa_.y = dpp_addf<0x124>(qa_.y); \
  qb_.x = dpp_addf<0x124>(qb_.x); qb_.y = dpp_addf<0x124>(qb_.y); \
  qa_.x = dpp_addf<0x128>(qa_.x); qa_.y = dpp_addf<0x128>(qa_.y); \
  qb_.x = dpp_addf<0x128>(qb_.x); qb_.y = dpp_addf<0x128>(qb_.y); \
  qa_.x = fmaf(my_e0, c0_, qa_.x); \
  /* delayed writeback of u_{i-1} (held in vp1) */ \
  Va[m_].x = (jg == jgo_) ? vp1a.x : Va[m_].x; \
  Va[m_].y = (jg == jgo_) ? vp1a.y : Va[m_].y; \
  Vb[m_].x = (jg == jgo_) ? vp1b.x : Vb[m_].x; \
  Vb[m_].y = (jg == jgo_) ? vp1b.y : Vb[m_].y; \
  /* rotate carried state (renamed by unroll) */ \
  vp2a = vp1a; vp2b = vp1b; \
  vp1a = vna_; vp1b = vnb_; \
  Pa = qa_; Pb = qb_; \
}

#define S4(N) STEPF((N) + 0) STEPF((N) + 1) STEPF((N) + 2) STEPF((N) + 3)
#define S16(N) S4((N) + 0) S4((N) + 4) S4((N) + 8) S4((N) + 12)

  // drain prologue LDS traffic so lgkm counts are ours alone
  asm volatile("s_waitcnt lgkmcnt(0)" ::: "memory");
  PFROW(0) PFROW(1) PFROW(2)  // 3 in flight

  #pragma unroll 1
  for (int it = 0; it < max_iter; ++it) {
    S16(0) S16(16) S16(32) S16(48)
  }

  // final pending writeback: u_63 in vp1 -> j0=63 (jg==15, m=3)
  Va[3].x = (jg == 15) ? vp1a.x : Va[3].x;
  Va[3].y = (jg == 15) ? vp1a.y : Va[3].y;
  Vb[3].x = (jg == 15) ? vp1b.x : Vb[3].x;
  Vb[3].y = (jg == 15) ? vp1b.y : Vb[3].y;

  // ---- epilogue: transpose k=0 slice via LDS (C is dead), coalesced out ----
  asm volatile("s_waitcnt lgkmcnt(0)" ::: "memory");  // retire ring tail reads
  __syncthreads();
  {
    float* Lw = Ls + (t >> 6) * 64;
    if (kq == 0) {  // k=0 lives in Va[m].x of row 0
      Lw[jg +  0] = Va[0].x;
      Lw[jg + 16] = Va[1].x;
      Lw[jg + 32] = Va[2].x;
      Lw[jg + 48] = Va[3].x;
    }
    __builtin_amdgcn_s_waitcnt(0);  // lgkm drain (same-wave store->load)
    float cv = -Lw[l];
    cv = fminf(fmaxf(cv, -1.f + 1e-6f), 1.f - 1e-6f);
    out[b * NV + l] = acosf(cv) * (1.f / PI_F);
  }
}

extern "C" void kernel_launch(void* const* d_in, const int* in_sizes, int n_in,
                              void* d_out, int out_size, void* d_ws, size_t ws_size,
                              hipStream_t stream) {
  const float* z = (const float*)d_in[0];
  const float* S = (const float*)d_in[1];
  const float* w = (const float*)d_in[2];
  const float* r = (const float*)d_in[3];
  const int* max_iter = (const int*)d_in[4];
  float* Cg = (float*)d_ws;

  const int nsplit = (ws_size >= (size_t)8 * CBUF * 4) ? 8
                   : (ws_size >= (size_t)4 * CBUF * 4) ? 4 : 1;
  compute_C_kernel<<<dim3(NV, nsplit), 128, 0, stream>>>(S, w, Cg, nsplit);
  mixing_kernel<<<BATCH / 4, 256, 0, stream>>>(z, r, Cg, max_iter,
                                               (float*)d_out, nsplit);
}

// Round 7
// 141.727 us; speedup vs baseline: 1.1314x; 1.1314x over previous
//
#include <hip/hip_runtime.h>
#include <math.h>

// Problem constants (match reference)
#define BATCH 1024
#define NV    64      // N_VARS
#define MC    256     // M_CLAUSES
#define KD    12      // K_DIM
#define PI_F  3.14159265358979323846f

// Compact permuted C layout (floats, per m-split copy):
//   rows: 64 x 64. Row q = Gram row of 1-based var v = (q+1)%64+1 (0-based
//     target jv = (q+1)&63), cols {jv, jv-1, jv-2} (wrapped) PRE-ZEROED.
//   Within-row position perm(j0) = (j0&7)*8 + (j0>>3): lane group jgx reads a
//     CONTIGUOUS 8-float slice (j0 === jgx mod 8) = 2 ds_read_b128.
//   c0N[64]  at C0OFF : c0N[q]   = C[v][0]
//   DgA[64]  at DGAOFF: DgA[v-1] = C[v][prev1(v)]  -> readlane i gives C[i][i-1]
//   DgB[64]  at DGBOFF: DgB[v-1] = C[v][prev2(v)]  -> readlane i gives C[i][i-2]
#define C0OFF  4096
#define DGAOFF 4160
#define DGBOFF 4224
#define CBUF   4288

typedef float f2  __attribute__((ext_vector_type(2)));
typedef float v4f __attribute__((ext_vector_type(4)));
typedef __attribute__((address_space(3))) float lds_f;

// ---- DPP add helpers (bound_ctrl=true, old=0 -> GCNDPPCombine-fusable) ----
// 0xB1 quad xor1 (lane bit0), 0x4E quad xor2 (bit1), 0x128 row_ror:8 == xor8
// within a 16-row (bit3, exact), 0x124 row_ror:4 (== xor4 when the operand is
// uniform over bits {0,1,3} -- our n2 partials are), 0x142 row_bcast15,
// 0x143 row_bcast31.
template <int CTRL>
__device__ __forceinline__ float dpp_addf(float x) {
  int y = __builtin_amdgcn_update_dpp(0, __float_as_int(x), CTRL, 0xF, 0xF, true);
  return x + __int_as_float(y);
}
__device__ __forceinline__ float readlane63(float x) {
  return __int_as_float(__builtin_amdgcn_readlane(__float_as_int(x), 63));
}
__device__ __forceinline__ float rlane(float x, int i) {
  return __int_as_float(__builtin_amdgcn_readlane(__float_as_int(x), i));
}

// Async LDS read: volatile pins the ISSUE point; the counted s_waitcnt carries
// consume-side ordering through REGISTER deps ("+v" on the slot), no memory
// clobber / sched_barrier -> independent VALU schedules freely across steps.
template <int IMM>
__device__ __forceinline__ void dsr(v4f& d, unsigned base) {
  asm volatile("ds_read_b128 %0, %1 offset:%2" : "=v"(d) : "v"(base), "i"(IMM));
}

// ---- Kernel 1: Gram rows (permuted, pre-zeroed cols) + c0/dgA/dgB tables ----
__global__ void compute_C_kernel(const float* __restrict__ S,
                                 const float* __restrict__ w,
                                 float* __restrict__ Cg, int nsplit) {
  const int q = blockIdx.x;
  const int mc = blockIdx.y;
  const int j = threadIdx.x;  // column 0..64 (1-based vars; 0 = e0 row)
  if (j > NV) return;
  const int v = (q + 1) % 64 + 1;
  const int mlen = MC / nsplit;
  const int m0 = mc * mlen;
  float a0 = 0.f, a1 = 0.f, a2 = 0.f, a3 = 0.f;
  for (int m = m0; m < m0 + mlen; m += 4) {
    const float w0 = w[m], w1 = w[m + 1], w2 = w[m + 2], w3 = w[m + 3];
    a0 = fmaf(S[(m + 0) * (NV + 1) + v] * w0 * w0, S[(m + 0) * (NV + 1) + j], a0);
    a1 = fmaf(S[(m + 1) * (NV + 1) + v] * w1 * w1, S[(m + 1) * (NV + 1) + j], a1);
    a2 = fmaf(S[(m + 2) * (NV + 1) + v] * w2 * w2, S[(m + 2) * (NV + 1) + j], a2);
    a3 = fmaf(S[(m + 3) * (NV + 1) + v] * w3 * w3, S[(m + 3) * (NV + 1) + j], a3);
  }
  const float acc = (a0 + a1) + (a2 + a3);
  float* buf = Cg + mc * CBUF;
  const int p1 = (v == 1) ? 64 : (v - 1);
  const int p2 = (v == 1) ? 63 : (v == 2) ? 64 : (v - 2);
  if (j == 0) buf[C0OFF + q] = acc;
  if (j == p1) buf[DGAOFF + (v - 1)] = acc;
  if (j == p2) buf[DGBOFF + (v - 1)] = acc;
  if (j > 0) {
    const int j0 = j - 1;  // 0-based var column
    const float st = (j == v || j == p1 || j == p2) ? 0.f : acc;
    buf[q * 64 + (j0 & 7) * 8 + (j0 >> 3)] = st;  // permuted position
  }
}

// ---- Kernel 2: J=8 lane-split mixing, VGPR tables, 2 b128/step -------------
// Block = 256 thr = 4 waves = 4 batches, shared LDS C.
// Lane l: jgx = bit0|bit1|bit3 (8 groups) owns vars j0 === jgx (mod 8);
// kl = bit2|bit4|bit5 (8 k-pair slots) owns k = {2kl, 2kl+1} (kl>=6 pad=0).
// Per lane: Vv[8] f2 = V[jgx+8m][k-pair]. Carries P (=Q_i, jg-uniform),
// vp1/vp2 = u_{i-1}/u_{i-2}[k-pair] (jg-uniform).
// Step i (target var jv=i): g = P + da*vp1 + db*vp2 -> n2 reduce over k-lanes
// (ror4-as-xor4, bcast15, bcast31, readlane63) -> rsq -> vn; Q_{i+1} =
// 8 pk_fma + 3-hop jg butterfly (xor1,xor2,xor8) x 2 subregs + e0 term;
// delayed writeback of u_{i-1}. Tables via 3 v_readlane from VGPR-distributed
// copies (proven r0-r5; round-6's SMEM streaming crashed and is abandoned).
__global__ __launch_bounds__(256, 1) void mixing_kernel(
    const float* __restrict__ z, const float* __restrict__ r,
    const float* __restrict__ Cg, const int* __restrict__ max_iter_p,
    float* __restrict__ out, int nsplit) {
  __shared__ __align__(16) float Ls[CBUF];  // 17152 B

  const int t = threadIdx.x;
  const int l = t & 63;
  const int jgx = (l & 3) | ((l >> 1) & 4);          // lane bits 0,1,3
  const int kl = ((l >> 2) & 1) | ((l >> 3) & 6);    // lane bits 2,4,5
  const int b = blockIdx.x * 4 + (t >> 6);
  const int max_iter = max_iter_p[0];

  // stage (and m-split-reduce) compact C into LDS
  {
    const float4* src = (const float4*)Cg;
    float4* dst = (float4*)Ls;
    for (int idx = t; idx < CBUF / 4; idx += 256) {
      float4 a = src[idx];
      for (int u = 1; u < nsplit; ++u) {
        const float4 p = src[u * (CBUF / 4) + idx];
        a.x += p.x; a.y += p.y; a.z += p.z; a.w += p.w;
      }
      dst[idx] = a;
    }
  }

  const float my_e0 = (kl == 0) ? 1.f : 0.f;

  // ---- init: V[j][k] = -cos(pi z_j) [k=0] + sin(pi z_j) * rp_hat[k] ----
  f2 Vv[8];
  #pragma unroll
  for (int m = 0; m < 8; ++m) {
    const int j0 = jgx + 8 * m;
    const float zv = z[b * NV + j0];
    f2 rp = {0.f, 0.f};
    if (kl < 6) rp = *(const f2*)&r[(b * NV + j0) * KD + 2 * kl];
    if (kl == 0) rp.x = 0.f;  // k=0 excluded from r_perp
    float ssp = fmaf(rp.x, rp.x, rp.y * rp.y);
    ssp += __shfl_xor(ssp, 4, 64);    // k-bit 2
    ssp += __shfl_xor(ssp, 16, 64);   // k-bit 4
    ssp += __shfl_xor(ssp, 32, 64);   // k-bit 5
    const float inv = 1.f / fmaxf(sqrtf(ssp), 1e-8f);
    const float sn = __builtin_amdgcn_sinf(0.5f * zv);  // sin(pi*z)
    const float cs = __builtin_amdgcn_cosf(0.5f * zv);  // cos(pi*z)
    const float si = sn * inv;
    Vv[m].x = (kl == 0) ? -cs : si * rp.x;
    Vv[m].y = si * rp.y;
  }

  __syncthreads();

  // lane-distributed tables: lane x holds c0N[x], DgA[x], DgB[x]
  const float t0v = Ls[C0OFF + l];
  const float t1v = Ls[DGAOFF + l];
  const float t2v = Ls[DGBOFF + l];

  f2 P, vp1, vp2;

  // ---- prologue: Q for var 0 from row 63; vp1/vp2 = V_init[63/62] ----
  {
    const v4f cA = *(const v4f*)&Ls[63 * 64 + jgx * 8];
    const v4f cB = *(const v4f*)&Ls[63 * 64 + jgx * 8 + 4];
    f2 q = (f2){cA.x, cA.x} * Vv[0];
    q = __builtin_elementwise_fma((f2){cA.y, cA.y}, Vv[1], q);
    q = __builtin_elementwise_fma((f2){cA.z, cA.z}, Vv[2], q);
    q = __builtin_elementwise_fma((f2){cA.w, cA.w}, Vv[3], q);
    q = __builtin_elementwise_fma((f2){cB.x, cB.x}, Vv[4], q);
    q = __builtin_elementwise_fma((f2){cB.y, cB.y}, Vv[5], q);
    q = __builtin_elementwise_fma((f2){cB.z, cB.z}, Vv[6], q);
    q = __builtin_elementwise_fma((f2){cB.w, cB.w}, Vv[7], q);
    q.x = dpp_addf<0xB1>(q.x);  q.y = dpp_addf<0xB1>(q.y);
    q.x = dpp_addf<0x4E>(q.x);  q.y = dpp_addf<0x4E>(q.y);
    q.x = dpp_addf<0x128>(q.x); q.y = dpp_addf<0x128>(q.y);
    q.x = fmaf(my_e0, Ls[C0OFF + 63], q.x);
    P = q;
    // j0=63 -> jgx=7 (lane bits 0,1,3 = 1); j0=62 -> jgx=6 (bits 1,3 = 1)
    vp1.x = __shfl(Vv[7].x, (l & 0x34) | 0x0B, 64);
    vp1.y = __shfl(Vv[7].y, (l & 0x34) | 0x0B, 64);
    vp2.x = __shfl(Vv[7].x, (l & 0x34) | 0x0A, 64);
    vp2.y = __shfl(Vv[7].y, (l & 0x34) | 0x0A, 64);
  }

  // LDS byte base for this lane's 32B row slice
  const unsigned lbase = (unsigned)(unsigned long long)(lds_f*)&Ls[jgx * 8];

  v4f Rb[4][2];  // 4-row ring, 2 b128 per row, compile-time indexed

#define PFROW(R) \
  dsr<((((R) & 63) * 256) + 0)>(Rb[(R) & 3][0], lbase); \
  dsr<((((R) & 63) * 256) + 16)>(Rb[(R) & 3][1], lbase);

// Counted wait via REGISTER deps on the consumed slots. Outstanding at the
// wait point: rows i, i+1, i+2 = 6 ds_reads; lgkmcnt(4) retires row i's 2.
#define WAITR(SL) \
  asm volatile("s_waitcnt lgkmcnt(4)" : "+v"(Rb[SL][0]), "+v"(Rb[SL][1]));

#define STEPF(I) { \
  constexpr int i_ = (I); \
  constexpr int s_ = i_ & 3; \
  constexpr int j0w_ = (i_ + 63) & 63; \
  constexpr int m_ = j0w_ >> 3; \
  constexpr int jgo_ = j0w_ & 7; \
  WAITR(s_) \
  PFROW(i_ + 3) \
  const float da_ = rlane(t1v, i_); \
  const float db_ = rlane(t2v, i_); \
  const float c0_ = rlane(t0v, i_); \
  /* chain head: the true recurrence */ \
  f2 g_; \
  g_.x = fmaf(da_, vp1.x, fmaf(db_, vp2.x, P.x)); \
  g_.y = fmaf(da_, vp1.y, fmaf(db_, vp2.y, P.y)); \
  float t_ = fmaf(g_.x, g_.x, g_.y * g_.y); \
  const v4f ceA = Rb[s_][0], ceB = Rb[s_][1]; \
  f2 q_ = (f2){ceA.x, ceA.x} * Vv[0]; \
  q_ = __builtin_elementwise_fma((f2){ceA.y, ceA.y}, Vv[1], q_); \
  t_ = dpp_addf<0x124>(t_);            /* xor4 (valid: uniform over jg) */ \
  q_ = __builtin_elementwise_fma((f2){ceA.z, ceA.z}, Vv[2], q_); \
  q_ = __builtin_elementwise_fma((f2){ceA.w, ceA.w}, Vv[3], q_); \
  t_ = dpp_addf<0x142>(t_);            /* row1+=row0, row3+=row2 */ \
  q_ = __builtin_elementwise_fma((f2){ceB.x, ceB.x}, Vv[4], q_); \
  q_ = __builtin_elementwise_fma((f2){ceB.y, ceB.y}, Vv[5], q_); \
  t_ = dpp_addf<0x143>(t_);            /* lane63 = total */ \
  q_ = __builtin_elementwise_fma((f2){ceB.z, ceB.z}, Vv[6], q_); \
  q_ = __builtin_elementwise_fma((f2){ceB.w, ceB.w}, Vv[7], q_); \
  const float n2_ = readlane63(t_); \
  const float inv_ = __builtin_amdgcn_rsqf(fmaxf(n2_, 1e-16f)); \
  q_.x = dpp_addf<0xB1>(q_.x);  q_.y = dpp_addf<0xB1>(q_.y); \
  f2 vn_; vn_.x = -g_.x * inv_; vn_.y = -g_.y * inv_; \
  q_.x = dpp_addf<0x4E>(q_.x);  q_.y = dpp_addf<0x4E>(q_.y); \
  q_.x = dpp_addf<0x128>(q_.x); q_.y = dpp_addf<0x128>(q_.y); \
  q_.x = fmaf(my_e0, c0_, q_.x); \
  /* delayed writeback of u_{i-1} (held in vp1) */ \
  Vv[m_].x = (jgx == jgo_) ? vp1.x : Vv[m_].x; \
  Vv[m_].y = (jgx == jgo_) ? vp1.y : Vv[m_].y; \
  /* rotate carried state (renamed by unroll) */ \
  vp2 = vp1; vp1 = vn_; P = q_; \
}

#define S4(N) STEPF((N) + 0) STEPF((N) + 1) STEPF((N) + 2) STEPF((N) + 3)
#define S16(N) S4((N) + 0) S4((N) + 4) S4((N) + 8) S4((N) + 12)

  // drain prologue LDS traffic so lgkm counts are ours alone
  asm volatile("s_waitcnt lgkmcnt(0)" ::: "memory");
  PFROW(0) PFROW(1) PFROW(2)  // 6 ds_reads in flight

  #pragma unroll 1
  for (int it = 0; it < max_iter; ++it) {
    S16(0) S16(16) S16(32) S16(48)
  }

  // final pending writeback: u_63 in vp1 -> j0=63 (jgx==7, m=7)
  Vv[7].x = (jgx == 7) ? vp1.x : Vv[7].x;
  Vv[7].y = (jgx == 7) ? vp1.y : Vv[7].y;

  // ---- epilogue: transpose k=0 slice via LDS (rows dead), coalesced out ----
  asm volatile("s_waitcnt lgkmcnt(0)" ::: "memory");  // retire ring tail reads
  __syncthreads();
  {
    float* Lw = Ls + (t >> 6) * 64;
    if (kl == 0) {  // k=0 lives in Vv[m].x of k-slot-0 lanes
      #pragma unroll
      for (int m = 0; m < 8; ++m) Lw[jgx + 8 * m] = Vv[m].x;
    }
    __builtin_amdgcn_s_waitcnt(0);  // lgkm drain (same-wave store->load)
    float cv = -Lw[l];
    cv = fminf(fmaxf(cv, -1.f + 1e-6f), 1.f - 1e-6f);
    out[b * NV + l] = acosf(cv) * (1.f / PI_F);
  }
}

extern "C" void kernel_launch(void* const* d_in, const int* in_sizes, int n_in,
                              void* d_out, int out_size, void* d_ws, size_t ws_size,
                              hipStream_t stream) {
  const float* z = (const float*)d_in[0];
  const float* S = (const float*)d_in[1];
  const float* w = (const float*)d_in[2];
  const float* r = (const float*)d_in[3];
  const int* max_iter = (const int*)d_in[4];
  float* Cg = (float*)d_ws;

  const int nsplit = (ws_size >= (size_t)8 * CBUF * 4) ? 8
                   : (ws_size >= (size_t)4 * CBUF * 4) ? 4 : 1;
  compute_C_kernel<<<dim3(NV, nsplit), 128, 0, stream>>>(S, w, Cg, nsplit);
  mixing_kernel<<<BATCH / 4, 256, 0, stream>>>(z, r, Cg, max_iter,
                                               (float*)d_out, nsplit);
}